// Round 4
// baseline (336.681 us; speedup 1.0000x reference)
//
#include <hip/hip_runtime.h>

#define B_   64
#define T_   1024
#define C_   256
#define NEGF (-4294967295.0f)   // float(-2**32+1) == -2^32, matches reference fp32 cast
#define LN_EPS 1e-9f

typedef short  short8 __attribute__((ext_vector_type(8)));
typedef float  f32x4  __attribute__((ext_vector_type(4)));

union S8 { short8 v; unsigned int w[4]; };

// float -> bf16 (RNE), packed pair
__device__ __forceinline__ unsigned int pk2(float x, float y) {
  unsigned a = __float_as_uint(x); a = (a + 0x7fffu + ((a >> 16) & 1u)) >> 16;
  unsigned b = __float_as_uint(y); b = (b + 0x7fffu + ((b >> 16) & 1u)) >> 16;
  return a | (b << 16);
}

// async global->LDS, 16 B per lane, lands at ldsbase + lane*16
__device__ __forceinline__ void async16(const void* g, void* l) {
  __builtin_amdgcn_global_load_lds(
      (const __attribute__((address_space(1))) void*)g,
      (__attribute__((address_space(3))) void*)l,
      16, 0, 0);
}

// ---------------- small kernels ----------------

__global__ void detect_kernel(const unsigned int* __restrict__ mw,
                              int* __restrict__ flag) {
  int idx = blockIdx.x * 256 + threadIdx.x;   // 16384 words, safe for u8 or i32 buffer
  if (mw[idx] > 1u) atomicOr(flag, 1);
}

// sb[b*T+j] = mask ? (1/16, 0) : (0, NEGF)   -> score = s*scale + bias
__global__ void build_sb(const unsigned int* __restrict__ mw,
                         const int* __restrict__ flag,
                         float2* __restrict__ sb) {
  int idx = blockIdx.x * 256 + threadIdx.x;   // B*T = 65536
  int f = *flag;
  unsigned int w = mw[f ? (idx >> 2) : idx];
  unsigned int v = f ? ((w >> ((idx & 3) * 8)) & 0xffu) : w;
  sb[idx] = v ? make_float2(0.0625f, 0.f) : make_float2(0.f, NEGF);
}

__global__ void finalize_kernel(const float* __restrict__ accum,
                                float* __restrict__ out) {
  int idx = blockIdx.x * 256 + threadIdx.x;   // B*C = 16384
  out[idx] = accum[idx] * (1.0f / T_);
}

// ---------------- pre-pass: bf16 K image + V^T image + colsum ----------------
// One block per (b, 32-row tile). No LDS: phase 2 transposes via coalesced
// re-reads of the L2-hot rows (no barrier, no bank conflicts).
__global__ __launch_bounds__(256) void convert_kv(const float* __restrict__ x,
                                                  short* __restrict__ xk,
                                                  short* __restrict__ xv,
                                                  float* __restrict__ colsum) {
  const int blk = blockIdx.x, b = blk >> 5, tt = blk & 31;
  const int tid = threadIdx.x;
  const float* xt = x + (size_t)(b * 1024 + tt * 32) * 256;

  // phase 1: coalesced row reads -> swizzled bf16 K-image
#pragma unroll
  for (int u = 0; u < 4; ++u) {
    int id = u * 256 + tid;            // 1024 items: 32 rows x 32 chunks
    int row = id >> 5, ck = id & 31;
    const float* src = xt + row * 256 + ck * 8;
    float4 a  = *(const float4*)src;
    float4 c4 = *(const float4*)(src + 4);
    S8 s; s.w[0] = pk2(a.x, a.y);  s.w[1] = pk2(a.z, a.w);
          s.w[2] = pk2(c4.x, c4.y); s.w[3] = pk2(c4.z, c4.w);
    *(short8*)(xk + (size_t)(b * 1024 + tt * 32 + row) * 256 + ((ck ^ row) << 3)) = s.v;
  }

  // phase 2: column-slices (coalesced over c across lanes) -> swizzled V^T + colsum
  const int ck = tid >> 6, clo = tid & 63;
  short* vout = xv + (size_t)(b * 32 + tt) * 8192;
#pragma unroll
  for (int g = 0; g < 4; ++g) {
    int c = g * 64 + clo;
    float vs[8]; float s = 0.f;
#pragma unroll
    for (int e = 0; e < 8; ++e) { vs[e] = xt[(ck * 8 + e) * 256 + c]; s += vs[e]; }
    S8 o;
    o.w[0] = pk2(vs[0], vs[1]); o.w[1] = pk2(vs[2], vs[3]);
    o.w[2] = pk2(vs[4], vs[5]); o.w[3] = pk2(vs[6], vs[7]);
    *(short8*)(vout + c * 32 + (((ck ^ ((c >> 1) & 3)) & 3) << 3)) = o.v;
    atomicAdd(&colsum[b * 256 + c], s);
  }
}

// ---------------- flash kernel ----------------
// 512 blocks (all co-resident: 2/CU), block = (batch b, 128-row q-tile t).
// blockIdx mapping: XCD i%8 hosts batches 8x..8x+7; the two blocks on a CU
// get q-tiles (t, 7-t) for load balance; all 8 q-tiles of a batch stream the
// same key tiles in lockstep -> per-XCD L2 serves each tile once per batch.
// Wave w owns 32 q-rows (2 n-tiles). 32-key tiles, double-buffered DMA.
__global__ __launch_bounds__(256, 2) void flash3(
    const short* __restrict__ xk,
    const short* __restrict__ xv,
    const float2* __restrict__ sb,
    const float* __restrict__ gamma,
    const float* __restrict__ beta,
    const float* __restrict__ colsum,
    float* __restrict__ accum)
{
  __shared__ __align__(16) short KsD[2][32 * 256];   // 2 x 16 KB
  __shared__ __align__(16) short VtD[2][256 * 32];   // 2 x 16 KB

  const int i0 = blockIdx.x;
  const int x8 = i0 & 7;
  const int s  = i0 >> 3;
  int b, t;
  if (s < 32) { b = x8 * 8 + (s & 7); t = s >> 3; }
  else        { int s2 = s - 32; b = x8 * 8 + (s2 & 7); t = 7 - (s2 >> 3); }

  const int tid  = threadIdx.x;
  const int w    = tid >> 6;
  const int lane = tid & 63;
  const int quad = lane >> 4;
  const int r    = lane & 15;
  const int n0   = t * 128 + w * 32;       // wave's first q row
  const int nk   = 4 * (t + 1);            // number of 32-key tiles

  // ---- Q fragments for both n-tiles (from pre-swizzled bf16 K image)
  short8 qf[2][8];
#pragma unroll
  for (int nt = 0; nt < 2; ++nt) {
    const int qrow = n0 + nt * 16 + r;
    const short* qp = xk + (size_t)(b * 1024 + qrow) * 256;
#pragma unroll
    for (int ks = 0; ks < 8; ++ks)
      qf[nt][ks] = *(const short8*)(qp + (((ks * 4 + quad) ^ (qrow & 31)) << 3));
  }

  f32x4 Oa[2][16];
#pragma unroll
  for (int nt = 0; nt < 2; ++nt)
#pragma unroll
    for (int ct = 0; ct < 16; ++ct) Oa[nt][ct] = (f32x4){0.f, 0.f, 0.f, 0.f};
  float m0 = NEGF, l0 = 0.f, m1 = NEGF, l1 = 0.f;

  // prefetch tile 0 into buf 0
  {
    const short* gk = xk + (size_t)(b * 1024) * 256;
    const short* gv = xv + (size_t)(b * 32) * 8192;
#pragma unroll
    for (int u = 0; u < 4; ++u) {
      int is = w * 4 + u;
      async16(gk + is * 512 + lane * 8, &KsD[0][is * 512]);
      async16(gv + is * 512 + lane * 8, &VtD[0][is * 512]);
    }
  }
  __syncthreads();

  for (int kt = 0; kt < nk; ++kt) {
    const int ibuf = kt & 1;
    if (kt + 1 < nk) {   // async prefetch next tile into other buffer
      const short* gk = xk + (size_t)(b * 1024 + (kt + 1) * 32) * 256;
      const short* gv = xv + (size_t)(b * 32 + (kt + 1)) * 8192;
#pragma unroll
      for (int u = 0; u < 4; ++u) {
        int is = w * 4 + u;
        async16(gk + is * 512 + lane * 8, &KsD[1 - ibuf][is * 512]);
        async16(gv + is * 512 + lane * 8, &VtD[1 - ibuf][is * 512]);
      }
    }

    const int ktb = kt * 32;
    if (ktb <= n0 + 31) {   // wave-uniform causal tile skip
      // ---- scores S^T = K·Q^T for both n-tiles (A-frags shared)
      float sc0[8], sc1[8];
#pragma unroll
      for (int mt = 0; mt < 2; ++mt) {
        f32x4 a0 = (f32x4){0.f, 0.f, 0.f, 0.f};
        f32x4 a1 = (f32x4){0.f, 0.f, 0.f, 0.f};
        const int row = mt * 16 + r;
#pragma unroll
        for (int ks = 0; ks < 8; ++ks) {
          short8 af = *(short8*)&KsD[ibuf][row * 256 + (((ks * 4 + quad) ^ row) << 3)];
          a0 = __builtin_amdgcn_mfma_f32_16x16x32_bf16(af, qf[0][ks], a0, 0, 0, 0);
          a1 = __builtin_amdgcn_mfma_f32_16x16x32_bf16(af, qf[1][ks], a1, 0, 0, 0);
        }
        const int j0 = ktb + mt * 16 + quad * 4;
        float4 sA = *(const float4*)(sb + (size_t)b * 1024 + j0);     // s0,b0,s1,b1
        float4 sB = *(const float4*)(sb + (size_t)b * 1024 + j0 + 2); // s2,b2,s3,b3
        sc0[mt * 4 + 0] = a0[0] * sA.x + sA.y;
        sc0[mt * 4 + 1] = a0[1] * sA.z + sA.w;
        sc0[mt * 4 + 2] = a0[2] * sB.x + sB.y;
        sc0[mt * 4 + 3] = a0[3] * sB.z + sB.w;
        sc1[mt * 4 + 0] = a1[0] * sA.x + sA.y;
        sc1[mt * 4 + 1] = a1[1] * sA.z + sA.w;
        sc1[mt * 4 + 2] = a1[2] * sB.x + sB.y;
        sc1[mt * 4 + 3] = a1[3] * sB.z + sB.w;
      }
      if (ktb + 31 > n0) {   // diagonal region: elementwise causal mask
#pragma unroll
        for (int k2 = 0; k2 < 8; ++k2) {
          int j = ktb + (k2 >> 2) * 16 + quad * 4 + (k2 & 3);
          if (j > n0 + r)      sc0[k2] = NEGF;
          if (j > n0 + 16 + r) sc1[k2] = NEGF;
        }
      }

      // ---- online softmax + PV A-frag, per n-tile
      S8 pf0, pf1;
      {
        float mx = sc0[0];
#pragma unroll
        for (int k2 = 1; k2 < 8; ++k2) mx = fmaxf(mx, sc0[k2]);
        mx = fmaxf(mx, __shfl_xor(mx, 16, 64));
        mx = fmaxf(mx, __shfl_xor(mx, 32, 64));
        float mnew  = fmaxf(m0, mx);
        float alpha = __expf(m0 - mnew);   // NEGF-NEGF=0 -> 1; NEGF-real -> 0
        float p[8], ps = 0.f;
#pragma unroll
        for (int k2 = 0; k2 < 8; ++k2) { p[k2] = __expf(sc0[k2] - mnew); ps += p[k2]; }
        ps += __shfl_xor(ps, 16, 64);
        ps += __shfl_xor(ps, 32, 64);
        l0 = l0 * alpha + ps;
        m0 = mnew;
        if (__ballot(alpha < 1.0f)) {
          float ar[4];
#pragma unroll
          for (int reg = 0; reg < 4; ++reg) ar[reg] = __shfl(alpha, quad * 4 + reg, 64);
#pragma unroll
          for (int ct = 0; ct < 16; ++ct) {
            Oa[0][ct][0] *= ar[0]; Oa[0][ct][1] *= ar[1];
            Oa[0][ct][2] *= ar[2]; Oa[0][ct][3] *= ar[3];
          }
        }
        unsigned q0 = pk2(p[0], p[1]), q1 = pk2(p[2], p[3]);
        unsigned q2 = pk2(p[4], p[5]), q3 = pk2(p[6], p[7]);
        int s0l = ((quad & 1) << 5) + r, s1l = s0l + 16;
        unsigned u0 = __shfl((int)q0, s0l, 64), u1 = __shfl((int)q1, s0l, 64);
        unsigned u2 = __shfl((int)q2, s0l, 64), u3 = __shfl((int)q3, s0l, 64);
        unsigned v0 = __shfl((int)q0, s1l, 64), v1 = __shfl((int)q1, s1l, 64);
        unsigned v2 = __shfl((int)q2, s1l, 64), v3 = __shfl((int)q3, s1l, 64);
        bool hi = quad >= 2;
        pf0.w[0] = hi ? u2 : u0; pf0.w[1] = hi ? u3 : u1;
        pf0.w[2] = hi ? v2 : v0; pf0.w[3] = hi ? v3 : v1;
      }
      {
        float mx = sc1[0];
#pragma unroll
        for (int k2 = 1; k2 < 8; ++k2) mx = fmaxf(mx, sc1[k2]);
        mx = fmaxf(mx, __shfl_xor(mx, 16, 64));
        mx = fmaxf(mx, __shfl_xor(mx, 32, 64));
        float mnew  = fmaxf(m1, mx);
        float alpha = __expf(m1 - mnew);
        float p[8], ps = 0.f;
#pragma unroll
        for (int k2 = 0; k2 < 8; ++k2) { p[k2] = __expf(sc1[k2] - mnew); ps += p[k2]; }
        ps += __shfl_xor(ps, 16, 64);
        ps += __shfl_xor(ps, 32, 64);
        l1 = l1 * alpha + ps;
        m1 = mnew;
        if (__ballot(alpha < 1.0f)) {
          float ar[4];
#pragma unroll
          for (int reg = 0; reg < 4; ++reg) ar[reg] = __shfl(alpha, quad * 4 + reg, 64);
#pragma unroll
          for (int ct = 0; ct < 16; ++ct) {
            Oa[1][ct][0] *= ar[0]; Oa[1][ct][1] *= ar[1];
            Oa[1][ct][2] *= ar[2]; Oa[1][ct][3] *= ar[3];
          }
        }
        unsigned q0 = pk2(p[0], p[1]), q1 = pk2(p[2], p[3]);
        unsigned q2 = pk2(p[4], p[5]), q3 = pk2(p[6], p[7]);
        int s0l = ((quad & 1) << 5) + r, s1l = s0l + 16;
        unsigned u0 = __shfl((int)q0, s0l, 64), u1 = __shfl((int)q1, s0l, 64);
        unsigned u2 = __shfl((int)q2, s0l, 64), u3 = __shfl((int)q3, s0l, 64);
        unsigned v0 = __shfl((int)q0, s1l, 64), v1 = __shfl((int)q1, s1l, 64);
        unsigned v2 = __shfl((int)q2, s1l, 64), v3 = __shfl((int)q3, s1l, 64);
        bool hi = quad >= 2;
        pf1.w[0] = hi ? u2 : u0; pf1.w[1] = hi ? u3 : u1;
        pf1.w[2] = hi ? v2 : v0; pf1.w[3] = hi ? v3 : v1;
      }

      // ---- PV: B-frags (V) shared across both n-tiles
#pragma unroll
      for (int ct = 0; ct < 16; ++ct) {
        int c = ct * 16 + r;
        short8 bf = *(short8*)&VtD[ibuf][c * 32 + (((quad ^ ((c >> 1) & 3)) & 3) << 3)];
        Oa[0][ct] = __builtin_amdgcn_mfma_f32_16x16x32_bf16(pf0.v, bf, Oa[0][ct], 0, 0, 0);
        Oa[1][ct] = __builtin_amdgcn_mfma_f32_16x16x32_bf16(pf1.v, bf, Oa[1][ct], 0, 0, 0);
      }
    }
    __syncthreads();   // drains prefetched tile kt+1 (issued a full tile ago)
  } // kt

  // ---- finalize both n-tiles: 1/l (or colsum fallback), LN, partial time-sum
  float g_[16], be_[16], cs_[16];
#pragma unroll
  for (int ct = 0; ct < 16; ++ct) {
    int c = ct * 16 + r;
    cs_[ct] = colsum[b * C_ + c] * (1.0f / T_);
    g_[ct]  = gamma[c];
    be_[ct] = beta[c];
  }
#pragma unroll
  for (int nt = 0; nt < 2; ++nt) {
    float m = nt ? m1 : m0, l = nt ? l1 : l0;
    float mr[4], li[4];
#pragma unroll
    for (int reg = 0; reg < 4; ++reg) {
      mr[reg] = __shfl(m, quad * 4 + reg, 64);
      float lr = __shfl(l, quad * 4 + reg, 64);
      li[reg] = 1.f / lr;
    }
#pragma unroll
    for (int ct = 0; ct < 16; ++ct) {
#pragma unroll
      for (int reg = 0; reg < 4; ++reg) {
        Oa[nt][ct][reg] = (mr[reg] < -1.0e9f) ? cs_[ct] : Oa[nt][ct][reg] * li[reg];
      }
    }
    float ts[16];
#pragma unroll
    for (int ct = 0; ct < 16; ++ct) ts[ct] = 0.f;
#pragma unroll
    for (int reg = 0; reg < 4; ++reg) {
      float s2 = 0.f;
#pragma unroll
      for (int ct = 0; ct < 16; ++ct) s2 += Oa[nt][ct][reg];
      s2 += __shfl_xor(s2, 1, 64); s2 += __shfl_xor(s2, 2, 64);
      s2 += __shfl_xor(s2, 4, 64); s2 += __shfl_xor(s2, 8, 64);
      float mu = s2 * (1.0f / C_);
      float sq = 0.f;
#pragma unroll
      for (int ct = 0; ct < 16; ++ct) { float d = Oa[nt][ct][reg] - mu; sq += d * d; }
      sq += __shfl_xor(sq, 1, 64); sq += __shfl_xor(sq, 2, 64);
      sq += __shfl_xor(sq, 4, 64); sq += __shfl_xor(sq, 8, 64);
      float rstd = rsqrtf(sq * (1.0f / C_) + LN_EPS);
#pragma unroll
      for (int ct = 0; ct < 16; ++ct)
        ts[ct] += g_[ct] * (Oa[nt][ct][reg] - mu) * rstd + be_[ct];
    }
#pragma unroll
    for (int ct = 0; ct < 16; ++ct) {
      ts[ct] += __shfl_xor(ts[ct], 16, 64);
      ts[ct] += __shfl_xor(ts[ct], 32, 64);
    }
    if (quad == 0) {
#pragma unroll
      for (int ct = 0; ct < 16; ++ct)
        atomicAdd(&accum[b * C_ + ct * 16 + r], ts[ct]);
    }
  }
}

// ---------------- launch ----------------

extern "C" void kernel_launch(void* const* d_in, const int* in_sizes, int n_in,
                              void* d_out, int out_size, void* d_ws, size_t ws_size,
                              hipStream_t stream) {
  const float* x     = (const float*)d_in[0];
  const void*  km    = d_in[1];
  const float* gamma = (const float*)d_in[2];
  const float* beta  = (const float*)d_in[3];
  float* out = (float*)d_out;

  // ws layout
  const size_t off_sb = 131200;                       // float2[B*T] = 512 KB
  const size_t off_xk = 655616;                       // 32 MB bf16 K-image
  const size_t off_xv = off_xk + 33554432;            // 32 MB bf16 V^T-image

  float*  accum  = (float*)d_ws;
  float*  colsum = (float*)((char*)d_ws + 65536);
  int*    flag   = (int*)((char*)d_ws + 131072);
  float2* sb     = (float2*)((char*)d_ws + off_sb);
  short*  xk     = (short*)((char*)d_ws + off_xk);
  short*  xv     = (short*)((char*)d_ws + off_xv);

  hipMemsetAsync(d_ws, 0, 131200, stream);
  detect_kernel<<<64, 256, 0, stream>>>((const unsigned int*)km, flag);
  build_sb<<<B_ * T_ / 256, 256, 0, stream>>>((const unsigned int*)km, flag, sb);
  convert_kv<<<B_ * 32, 256, 0, stream>>>(x, xk, xv, colsum);
  flash3<<<512, 256, 0, stream>>>(xk, xv, sb, gamma, beta, colsum, accum);
  finalize_kernel<<<B_ * C_ / 256, 256, 0, stream>>>(accum, out);
}

// Round 5
// 245.355 us; speedup vs baseline: 1.3722x; 1.3722x over previous
//
#include <hip/hip_runtime.h>

#define B_   64
#define T_   1024
#define C_   256
#define NEGF (-4294967295.0f)   // float(-2**32+1) == -2^32, matches reference fp32 cast
#define LN_EPS 1e-9f

typedef short  short8 __attribute__((ext_vector_type(8)));
typedef float  f32x4  __attribute__((ext_vector_type(4)));

union S8 { short8 v; unsigned int w[4]; };

// float -> bf16 (RNE), packed pair
__device__ __forceinline__ unsigned int pk2(float x, float y) {
  unsigned a = __float_as_uint(x); a = (a + 0x7fffu + ((a >> 16) & 1u)) >> 16;
  unsigned b = __float_as_uint(y); b = (b + 0x7fffu + ((b >> 16) & 1u)) >> 16;
  return a | (b << 16);
}

__device__ __forceinline__ float fc(const float4& v, int e) {
  return e == 0 ? v.x : e == 1 ? v.y : e == 2 ? v.z : v.w;
}

// async global->LDS, 16 B per lane
__device__ __forceinline__ void async16(const void* g, void* l) {
  __builtin_amdgcn_global_load_lds(
      (const __attribute__((address_space(1))) void*)g,
      (__attribute__((address_space(3))) void*)l,
      16, 0, 0);
}

// ---------------- small kernels ----------------

__global__ void detect_kernel(const unsigned int* __restrict__ mw,
                              int* __restrict__ flag) {
  int idx = blockIdx.x * 256 + threadIdx.x;   // 16384 words, safe for u8 or i32 buffer
  if (mw[idx] > 1u) atomicOr(flag, 1);
}

__global__ void finalize_kernel(const float* __restrict__ accum,
                                float* __restrict__ out) {
  int idx = blockIdx.x * 256 + threadIdx.x;   // B*C = 16384
  out[idx] = accum[idx] * (1.0f / T_);
}

// ---------------- pre-pass: bf16 K image + V^T image + colsum + sb ----------------
// One block per (b, 32-row tile); x read exactly once via LDS staging.
__global__ __launch_bounds__(256) void convert_kv(const float* __restrict__ x,
                                                  const unsigned int* __restrict__ mw,
                                                  const int* __restrict__ flag,
                                                  short* __restrict__ xk,
                                                  short* __restrict__ xv,
                                                  float* __restrict__ colsum,
                                                  float2* __restrict__ sb) {
  __shared__ float Xt[32 * 256];   // 32 KB fp32 tile [j][c]
  const int blk = blockIdx.x, b = blk >> 5, tt = blk & 31;
  const int tid = threadIdx.x;
  const float* xt = x + (size_t)(b * 1024 + tt * 32) * 256;

  // sb entries for this block's 32 rows (score = s*scale + bias)
  if (tid < 32) {
    int idx = b * 1024 + tt * 32 + tid;
    int f = *flag;
    unsigned int w = mw[f ? (idx >> 2) : idx];
    unsigned int v = f ? ((w >> ((idx & 3) * 8)) & 0xffu) : w;
    sb[idx] = v ? make_float2(0.0625f, 0.f) : make_float2(0.f, NEGF);
  }

  // phase 1: coalesced row reads -> LDS fp32 + swizzled bf16 K-image
#pragma unroll
  for (int u = 0; u < 4; ++u) {
    int id = u * 256 + tid;            // 1024 items: 32 rows x 32 chunks
    int row = id >> 5, ck = id & 31;
    const float* src = xt + row * 256 + ck * 8;
    float4 a  = *(const float4*)src;
    float4 c4 = *(const float4*)(src + 4);
    *(float4*)&Xt[row * 256 + ck * 8]     = a;
    *(float4*)&Xt[row * 256 + ck * 8 + 4] = c4;
    S8 s; s.w[0] = pk2(a.x, a.y);  s.w[1] = pk2(a.z, a.w);
          s.w[2] = pk2(c4.x, c4.y); s.w[3] = pk2(c4.z, c4.w);
    *(short8*)(xk + (size_t)(b * 1024 + tt * 32 + row) * 256 + ((ck ^ row) << 3)) = s.v;
  }
  __syncthreads();

  // phase 2: transpose from LDS -> swizzled V^T image + colsum partials
  const int ck = tid >> 6, clo = tid & 63;
  short* vout = xv + (size_t)(b * 32 + tt) * 8192;
#pragma unroll
  for (int g = 0; g < 4; ++g) {
    int c = g * 64 + clo;
    float vs[8]; float s = 0.f;
#pragma unroll
    for (int e = 0; e < 8; ++e) { vs[e] = Xt[(ck * 8 + e) * 256 + c]; s += vs[e]; }
    S8 o;
    o.w[0] = pk2(vs[0], vs[1]); o.w[1] = pk2(vs[2], vs[3]);
    o.w[2] = pk2(vs[4], vs[5]); o.w[3] = pk2(vs[6], vs[7]);
    *(short8*)(vout + c * 32 + (((ck ^ ((c >> 1) & 3)) & 3) << 3)) = o.v;
    atomicAdd(&colsum[b * 256 + c], s);
  }
}

// ---------------- flash kernel ----------------
// 512 blocks, 2/CU, all co-resident. Block = (batch b, qt pair (p, 15-p));
// UNIFORM 34 tile-iterations per block: ascending 0..2p+1 for qt=p, then
// DESCENDING 31-2p..0 for qt=15-p  (tile(idx) = idx<2(p+1) ? idx : 33-idx).
// In the descending phase every block of a batch is at tile 33-idx -> a batch
// touches exactly 2 tile streams at any instant; XCD clustering (blockIdx&7
// hosts batches = x mod 8) makes those streams L2-resident per XCD.
// Wave w owns 16 q rows. 32-key tiles, double-buffered async DMA staging.
__global__ __launch_bounds__(256, 2) void flash4(
    const short* __restrict__ xk,
    const short* __restrict__ xv,
    const float2* __restrict__ sb,
    const float* __restrict__ gamma,
    const float* __restrict__ beta,
    const float* __restrict__ colsum,
    float* __restrict__ accum)
{
  __shared__ __align__(16) short KsD[2][32 * 256];   // 2 x 16 KB
  __shared__ __align__(16) short VtD[2][256 * 32];   // 2 x 16 KB

  const int i0 = blockIdx.x;
  const int x8 = i0 & 7;            // XCD id (heuristic: round-robin dispatch)
  const int s  = i0 >> 3;           // 0..63
  const int b  = x8 + 8 * (s & 7);  // batches = x8 (mod 8) cluster on XCD x8
  const int pp = s >> 3;            // 0..7

  const int tid  = threadIdx.x;
  const int w    = tid >> 6;
  const int lane = tid & 63;
  const int quad = lane >> 4;
  const int r    = lane & 15;

  const int h0len = 2 * (pp + 1);   // ascending tiles for qt=pp

  // ---- state for current q-tile
  int   qt   = pp;
  int   n0   = qt * 64 + w * 16;
  int   qrow = n0 + r;
  short8 qf[8];
  {
    const short* qp = xk + (size_t)(b * 1024 + qrow) * 256;
#pragma unroll
    for (int ks = 0; ks < 8; ++ks)
      qf[ks] = *(const short8*)(qp + (((ks * 4 + quad) ^ (qrow & 31)) << 3));
  }
  f32x4 Oa[16];
#pragma unroll
  for (int ct = 0; ct < 16; ++ct) Oa[ct] = (f32x4){0.f, 0.f, 0.f, 0.f};
  float m = NEGF, l = 0.f;

  float g_[16], be_[16], cs_[16];
#pragma unroll
  for (int ct = 0; ct < 16; ++ct) {
    int c = ct * 16 + r;
    cs_[ct] = colsum[b * C_ + c] * (1.0f / T_);
    g_[ct]  = gamma[c];
    be_[ct] = beta[c];
  }

  // prefetch tile 0 into buf 0
  {
    const short* gk = xk + (size_t)(b * 1024) * 256;
    const short* gv = xv + (size_t)(b * 32) * 8192;
#pragma unroll
    for (int u = 0; u < 4; ++u) {
      int is = w * 4 + u;
      async16(gk + is * 512 + lane * 8, &KsD[0][is * 512]);
      async16(gv + is * 512 + lane * 8, &VtD[0][is * 512]);
    }
  }
  __syncthreads();

  for (int idx = 0; idx < 34; ++idx) {
    const int ibuf = idx & 1;
    if (idx < 33) {   // async prefetch tile(idx+1) into other buffer
      const int nt2 = (idx + 1 < h0len) ? (idx + 1) : (33 - (idx + 1));
      const short* gk = xk + (size_t)(b * 1024 + nt2 * 32) * 256;
      const short* gv = xv + (size_t)(b * 32 + nt2) * 8192;
#pragma unroll
      for (int u = 0; u < 4; ++u) {
        int is = w * 4 + u;
        async16(gk + is * 512 + lane * 8, &KsD[1 - ibuf][is * 512]);
        async16(gv + is * 512 + lane * 8, &VtD[1 - ibuf][is * 512]);
      }
    }

    const int kt  = (idx < h0len) ? idx : (33 - idx);
    const int ktb = kt * 32;
    if (ktb <= n0 + 15) {   // wave-uniform causal tile skip
      // ---- scores S^T = K·Q^T
      float sc[8];
#pragma unroll
      for (int mt = 0; mt < 2; ++mt) {
        f32x4 acc = (f32x4){0.f, 0.f, 0.f, 0.f};
        const int row = mt * 16 + r;
#pragma unroll
        for (int ks = 0; ks < 8; ++ks) {
          short8 af = *(short8*)&KsD[ibuf][row * 256 + (((ks * 4 + quad) ^ row) << 3)];
          acc = __builtin_amdgcn_mfma_f32_16x16x32_bf16(af, qf[ks], acc, 0, 0, 0);
        }
        const int j0 = ktb + mt * 16 + quad * 4;
        float4 sA = *(const float4*)(sb + (size_t)b * 1024 + j0);     // s0,b0,s1,b1
        float4 sB = *(const float4*)(sb + (size_t)b * 1024 + j0 + 2); // s2,b2,s3,b3
        sc[mt * 4 + 0] = acc[0] * sA.x + sA.y;
        sc[mt * 4 + 1] = acc[1] * sA.z + sA.w;
        sc[mt * 4 + 2] = acc[2] * sB.x + sB.y;
        sc[mt * 4 + 3] = acc[3] * sB.z + sB.w;
      }
      if (ktb + 31 > n0) {   // diagonal tiles: elementwise causal mask
#pragma unroll
        for (int k2 = 0; k2 < 8; ++k2) {
          int j = ktb + (k2 >> 2) * 16 + quad * 4 + (k2 & 3);
          if (j > qrow) sc[k2] = NEGF;
        }
      }

      // ---- online softmax (stats per q at lane&15, replicated via xor16/32)
      float mx = sc[0];
#pragma unroll
      for (int k2 = 1; k2 < 8; ++k2) mx = fmaxf(mx, sc[k2]);
      mx = fmaxf(mx, __shfl_xor(mx, 16, 64));
      mx = fmaxf(mx, __shfl_xor(mx, 32, 64));
      float mnew  = fmaxf(m, mx);
      float alpha = __expf(m - mnew);   // NEGF-NEGF=0 -> 1; NEGF-real -> 0
      float p[8], ps = 0.f;
#pragma unroll
      for (int k2 = 0; k2 < 8; ++k2) { p[k2] = __expf(sc[k2] - mnew); ps += p[k2]; }
      ps += __shfl_xor(ps, 16, 64);
      ps += __shfl_xor(ps, 32, 64);
      l = l * alpha + ps;
      m = mnew;

      if (__ballot(alpha < 1.0f)) {   // skip rescale when no max update anywhere
        float ar[4];
#pragma unroll
        for (int reg = 0; reg < 4; ++reg) ar[reg] = __shfl(alpha, quad * 4 + reg, 64);
#pragma unroll
        for (int ct = 0; ct < 16; ++ct) {
          Oa[ct][0] *= ar[0]; Oa[ct][1] *= ar[1];
          Oa[ct][2] *= ar[2]; Oa[ct][3] *= ar[3];
        }
      }

      // ---- P (C-layout) -> PV A-frag via 8 shuffles
      unsigned q0 = pk2(p[0], p[1]), q1 = pk2(p[2], p[3]);
      unsigned q2 = pk2(p[4], p[5]), q3 = pk2(p[6], p[7]);
      int s0l = ((quad & 1) << 5) + r, s1l = s0l + 16;
      unsigned u0 = __shfl((int)q0, s0l, 64), u1 = __shfl((int)q1, s0l, 64);
      unsigned u2 = __shfl((int)q2, s0l, 64), u3 = __shfl((int)q3, s0l, 64);
      unsigned v0 = __shfl((int)q0, s1l, 64), v1 = __shfl((int)q1, s1l, 64);
      unsigned v2 = __shfl((int)q2, s1l, 64), v3 = __shfl((int)q3, s1l, 64);
      bool hi = quad >= 2;
      S8 pf;
      pf.w[0] = hi ? u2 : u0; pf.w[1] = hi ? u3 : u1;
      pf.w[2] = hi ? v2 : v0; pf.w[3] = hi ? v3 : v1;

      // ---- PV: O[q][c] += P[q][j] V[j][c]
#pragma unroll
      for (int ct = 0; ct < 16; ++ct) {
        int c = ct * 16 + r;
        short8 bf = *(short8*)&VtD[ibuf][c * 32 + (((quad ^ ((c >> 1) & 3)) & 3) << 3)];
        Oa[ct] = __builtin_amdgcn_mfma_f32_16x16x32_bf16(pf.v, bf, Oa[ct], 0, 0, 0);
      }
    }

    // ---- boundary: finalize qt=pp, reset state for qt=15-pp (no LDS touched)
    if (idx == h0len - 1) {
      float mr[4], li[4];
#pragma unroll
      for (int reg = 0; reg < 4; ++reg) {
        mr[reg] = __shfl(m, quad * 4 + reg, 64);
        float lr = __shfl(l, quad * 4 + reg, 64);
        li[reg] = 1.f / lr;
      }
#pragma unroll
      for (int ct = 0; ct < 16; ++ct)
#pragma unroll
        for (int reg = 0; reg < 4; ++reg)
          Oa[ct][reg] = (mr[reg] < -1.0e9f) ? cs_[ct] : Oa[ct][reg] * li[reg];
      float ts[16];
#pragma unroll
      for (int ct = 0; ct < 16; ++ct) ts[ct] = 0.f;
#pragma unroll
      for (int reg = 0; reg < 4; ++reg) {
        float s2 = 0.f;
#pragma unroll
        for (int ct = 0; ct < 16; ++ct) s2 += Oa[ct][reg];
        s2 += __shfl_xor(s2, 1, 64); s2 += __shfl_xor(s2, 2, 64);
        s2 += __shfl_xor(s2, 4, 64); s2 += __shfl_xor(s2, 8, 64);
        float mu = s2 * (1.0f / C_);
        float sq = 0.f;
#pragma unroll
        for (int ct = 0; ct < 16; ++ct) { float d = Oa[ct][reg] - mu; sq += d * d; }
        sq += __shfl_xor(sq, 1, 64); sq += __shfl_xor(sq, 2, 64);
        sq += __shfl_xor(sq, 4, 64); sq += __shfl_xor(sq, 8, 64);
        float rstd = rsqrtf(sq * (1.0f / C_) + LN_EPS);
#pragma unroll
        for (int ct = 0; ct < 16; ++ct)
          ts[ct] += g_[ct] * (Oa[ct][reg] - mu) * rstd + be_[ct];
      }
#pragma unroll
      for (int ct = 0; ct < 16; ++ct) {
        ts[ct] += __shfl_xor(ts[ct], 16, 64);
        ts[ct] += __shfl_xor(ts[ct], 32, 64);
      }
      if (quad == 0) {
#pragma unroll
        for (int ct = 0; ct < 16; ++ct)
          atomicAdd(&accum[b * C_ + ct * 16 + r], ts[ct]);
      }
      // reset for second q-tile
      qt = 15 - pp;
      n0 = qt * 64 + w * 16;
      qrow = n0 + r;
      const short* qp = xk + (size_t)(b * 1024 + qrow) * 256;
#pragma unroll
      for (int ks = 0; ks < 8; ++ks)
        qf[ks] = *(const short8*)(qp + (((ks * 4 + quad) ^ (qrow & 31)) << 3));
#pragma unroll
      for (int ct = 0; ct < 16; ++ct) Oa[ct] = (f32x4){0.f, 0.f, 0.f, 0.f};
      m = NEGF; l = 0.f;
    }

    __syncthreads();   // drains prefetched tile(idx+1) (issued a full tile ago)
  } // idx

  // ---- finalize second q-tile (qt = 15-pp)
  {
    float mr[4], li[4];
#pragma unroll
    for (int reg = 0; reg < 4; ++reg) {
      mr[reg] = __shfl(m, quad * 4 + reg, 64);
      float lr = __shfl(l, quad * 4 + reg, 64);
      li[reg] = 1.f / lr;
    }
#pragma unroll
    for (int ct = 0; ct < 16; ++ct)
#pragma unroll
      for (int reg = 0; reg < 4; ++reg)
        Oa[ct][reg] = (mr[reg] < -1.0e9f) ? cs_[ct] : Oa[ct][reg] * li[reg];
    float ts[16];
#pragma unroll
    for (int ct = 0; ct < 16; ++ct) ts[ct] = 0.f;
#pragma unroll
    for (int reg = 0; reg < 4; ++reg) {
      float s2 = 0.f;
#pragma unroll
      for (int ct = 0; ct < 16; ++ct) s2 += Oa[ct][reg];
      s2 += __shfl_xor(s2, 1, 64); s2 += __shfl_xor(s2, 2, 64);
      s2 += __shfl_xor(s2, 4, 64); s2 += __shfl_xor(s2, 8, 64);
      float mu = s2 * (1.0f / C_);
      float sq = 0.f;
#pragma unroll
      for (int ct = 0; ct < 16; ++ct) { float d = Oa[ct][reg] - mu; sq += d * d; }
      sq += __shfl_xor(sq, 1, 64); sq += __shfl_xor(sq, 2, 64);
      sq += __shfl_xor(sq, 4, 64); sq += __shfl_xor(sq, 8, 64);
      float rstd = rsqrtf(sq * (1.0f / C_) + LN_EPS);
#pragma unroll
      for (int ct = 0; ct < 16; ++ct)
        ts[ct] += g_[ct] * (Oa[ct][reg] - mu) * rstd + be_[ct];
    }
#pragma unroll
    for (int ct = 0; ct < 16; ++ct) {
      ts[ct] += __shfl_xor(ts[ct], 16, 64);
      ts[ct] += __shfl_xor(ts[ct], 32, 64);
    }
    if (quad == 0) {
#pragma unroll
      for (int ct = 0; ct < 16; ++ct)
        atomicAdd(&accum[b * C_ + ct * 16 + r], ts[ct]);
    }
  }
}

// ---------------- launch ----------------

extern "C" void kernel_launch(void* const* d_in, const int* in_sizes, int n_in,
                              void* d_out, int out_size, void* d_ws, size_t ws_size,
                              hipStream_t stream) {
  const float* x     = (const float*)d_in[0];
  const void*  km    = d_in[1];
  const float* gamma = (const float*)d_in[2];
  const float* beta  = (const float*)d_in[3];
  float* out = (float*)d_out;

  // ws layout
  const size_t off_sb = 131200;                       // float2[B*T] = 512 KB
  const size_t off_xk = 655616;                       // 32 MB bf16 K-image
  const size_t off_xv = off_xk + 33554432;            // 32 MB bf16 V^T-image

  float*  accum  = (float*)d_ws;
  float*  colsum = (float*)((char*)d_ws + 65536);
  int*    flag   = (int*)((char*)d_ws + 131072);
  float2* sb     = (float2*)((char*)d_ws + off_sb);
  short*  xk     = (short*)((char*)d_ws + off_xk);
  short*  xv     = (short*)((char*)d_ws + off_xv);

  hipMemsetAsync(d_ws, 0, 131136, stream);   // accum + colsum + flag
  detect_kernel<<<64, 256, 0, stream>>>((const unsigned int*)km, flag);
  convert_kv<<<B_ * 32, 256, 0, stream>>>(x, (const unsigned int*)km, flag,
                                          xk, xv, colsum, sb);
  flash4<<<512, 256, 0, stream>>>(xk, xv, sb, gamma, beta, colsum, accum);
  finalize_kernel<<<B_ * C_ / 256, 256, 0, stream>>>(accum, out);
}

// Round 6
// 181.439 us; speedup vs baseline: 1.8556x; 1.3523x over previous
//
#include <hip/hip_runtime.h>

#define B_   64
#define T_   1024
#define C_   256
#define NEGF (-4294967295.0f)   // float(-2**32+1) == -2^32, matches reference fp32 cast
#define LN_EPS 1e-9f

typedef short  short8 __attribute__((ext_vector_type(8)));
typedef float  f32x4  __attribute__((ext_vector_type(4)));

union S8 { short8 v; unsigned int w[4]; };

// float -> bf16 (RNE), packed pair
__device__ __forceinline__ unsigned int pk2(float x, float y) {
  unsigned a = __float_as_uint(x); a = (a + 0x7fffu + ((a >> 16) & 1u)) >> 16;
  unsigned b = __float_as_uint(y); b = (b + 0x7fffu + ((b >> 16) & 1u)) >> 16;
  return a | (b << 16);
}

// async global->LDS, 16 B per lane
__device__ __forceinline__ void async16(const void* g, void* l) {
  __builtin_amdgcn_global_load_lds(
      (const __attribute__((address_space(1))) void*)g,
      (__attribute__((address_space(3))) void*)l,
      16, 0, 0);
}

// ---------------- small kernels ----------------

__global__ void detect_kernel(const unsigned int* __restrict__ mw,
                              int* __restrict__ flag) {
  int idx = blockIdx.x * 256 + threadIdx.x;   // 16384 words, safe for u8 or i32 buffer
  if (mw[idx] > 1u) atomicOr(flag, 1);
}

__global__ void finalize_kernel(const float* __restrict__ accum,
                                float* __restrict__ out) {
  int idx = blockIdx.x * 256 + threadIdx.x;   // B*C = 16384
  out[idx] = accum[idx] * (1.0f / T_);
}

// ---------------- pre-pass: bf16 K image + V^T image + colsum + sb ----------------
// One block per (b, 32-row tile); x read exactly once via LDS staging.
__global__ __launch_bounds__(256) void convert_kv(const float* __restrict__ x,
                                                  const unsigned int* __restrict__ mw,
                                                  const int* __restrict__ flag,
                                                  short* __restrict__ xk,
                                                  short* __restrict__ xv,
                                                  float* __restrict__ colsum,
                                                  float2* __restrict__ sb) {
  __shared__ float Xt[32 * 256];   // 32 KB fp32 tile [j][c]
  const int blk = blockIdx.x, b = blk >> 5, tt = blk & 31;
  const int tid = threadIdx.x;
  const float* xt = x + (size_t)(b * 1024 + tt * 32) * 256;

  // sb entries for this block's 32 rows (score = s*scale + bias)
  if (tid < 32) {
    int idx = b * 1024 + tt * 32 + tid;
    int f = *flag;
    unsigned int w = mw[f ? (idx >> 2) : idx];
    unsigned int v = f ? ((w >> ((idx & 3) * 8)) & 0xffu) : w;
    sb[idx] = v ? make_float2(0.0625f, 0.f) : make_float2(0.f, NEGF);
  }

  // phase 1: coalesced row reads -> LDS fp32 + swizzled bf16 K-image
#pragma unroll
  for (int u = 0; u < 4; ++u) {
    int id = u * 256 + tid;            // 1024 items: 32 rows x 32 chunks
    int row = id >> 5, ck = id & 31;
    const float* src = xt + row * 256 + ck * 8;
    float4 a  = *(const float4*)src;
    float4 c4 = *(const float4*)(src + 4);
    *(float4*)&Xt[row * 256 + ck * 8]     = a;
    *(float4*)&Xt[row * 256 + ck * 8 + 4] = c4;
    S8 s; s.w[0] = pk2(a.x, a.y);  s.w[1] = pk2(a.z, a.w);
          s.w[2] = pk2(c4.x, c4.y); s.w[3] = pk2(c4.z, c4.w);
    *(short8*)(xk + (size_t)(b * 1024 + tt * 32 + row) * 256 + ((ck ^ row) << 3)) = s.v;
  }
  __syncthreads();

  // phase 2: transpose from LDS -> swizzled V^T image + colsum partials
  const int ck = tid >> 6, clo = tid & 63;
  short* vout = xv + (size_t)(b * 32 + tt) * 8192;
#pragma unroll
  for (int g = 0; g < 4; ++g) {
    int c = g * 64 + clo;
    float vs[8]; float s = 0.f;
#pragma unroll
    for (int e = 0; e < 8; ++e) { vs[e] = Xt[(ck * 8 + e) * 256 + c]; s += vs[e]; }
    S8 o;
    o.w[0] = pk2(vs[0], vs[1]); o.w[1] = pk2(vs[2], vs[3]);
    o.w[2] = pk2(vs[4], vs[5]); o.w[3] = pk2(vs[6], vs[7]);
    *(short8*)(vout + c * 32 + (((ck ^ ((c >> 1) & 3)) & 3) << 3)) = o.v;
    atomicAdd(&colsum[b * 256 + c], s);
  }
}

// ---------------- flash finalize helper ----------------
__device__ __forceinline__ void finalize_tile(
    f32x4* Oa, float m, float l, int b, int quad, int r,
    const float* __restrict__ colsum, const float* __restrict__ gamma,
    const float* __restrict__ beta, float* __restrict__ accum)
{
  float mr[4], li[4];
#pragma unroll
  for (int reg = 0; reg < 4; ++reg) {
    mr[reg] = __shfl(m, quad * 4 + reg, 64);
    float lr = __shfl(l, quad * 4 + reg, 64);
    li[reg] = 1.f / lr;
  }
#pragma unroll
  for (int ct = 0; ct < 16; ++ct) {
    float cs = colsum[b * C_ + ct * 16 + r] * (1.0f / T_);
#pragma unroll
    for (int reg = 0; reg < 4; ++reg)
      Oa[ct][reg] = (mr[reg] < -1.0e9f) ? cs : Oa[ct][reg] * li[reg];
  }
  float ts[16];
#pragma unroll
  for (int ct = 0; ct < 16; ++ct) ts[ct] = 0.f;
#pragma unroll
  for (int reg = 0; reg < 4; ++reg) {
    float s2 = 0.f;
#pragma unroll
    for (int ct = 0; ct < 16; ++ct) s2 += Oa[ct][reg];
    s2 += __shfl_xor(s2, 1, 64); s2 += __shfl_xor(s2, 2, 64);
    s2 += __shfl_xor(s2, 4, 64); s2 += __shfl_xor(s2, 8, 64);
    float mu = s2 * (1.0f / C_);
    float sq = 0.f;
#pragma unroll
    for (int ct = 0; ct < 16; ++ct) { float d = Oa[ct][reg] - mu; sq += d * d; }
    sq += __shfl_xor(sq, 1, 64); sq += __shfl_xor(sq, 2, 64);
    sq += __shfl_xor(sq, 4, 64); sq += __shfl_xor(sq, 8, 64);
    float rstd = rsqrtf(sq * (1.0f / C_) + LN_EPS);
#pragma unroll
    for (int ct = 0; ct < 16; ++ct) {
      int c = ct * 16 + r;
      ts[ct] += gamma[c] * (Oa[ct][reg] - mu) * rstd + beta[c];
    }
  }
#pragma unroll
  for (int ct = 0; ct < 16; ++ct) {
    ts[ct] += __shfl_xor(ts[ct], 16, 64);
    ts[ct] += __shfl_xor(ts[ct], 32, 64);
  }
  if (quad == 0) {
#pragma unroll
    for (int ct = 0; ct < 16; ++ct)
      atomicAdd(&accum[b * C_ + ct * 16 + r], ts[ct]);
  }
}

// ---------------- flash kernel ----------------
// 256 blocks of 512 threads (8 waves), 1 block/CU, 128 KB LDS.
// Block = (batch b, 128-row q-tile pair (t, 7-t)); UNIFORM 18 iterations of
// 64-key tiles: ascending 0..2(t+1)-1 for qt=t, then descending 15-2t..0 for
// qt=7-t (kt = idx < h0len ? idx : 17-idx). All blocks of a batch touch <=2
// tile streams at any instant; XCD clustering (blockIdx&7 hosts batches = x
// mod 8) keeps those streams L2-resident. Wave owns 16 q rows. Double-
// buffered async DMA staging (64 KB/tile), ONE barrier per 64-key tile.
__global__ __launch_bounds__(512, 2) void flash5(
    const short* __restrict__ xk,
    const short* __restrict__ xv,
    const float2* __restrict__ sb,
    const float* __restrict__ gamma,
    const float* __restrict__ beta,
    const float* __restrict__ colsum,
    float* __restrict__ accum)
{
  __shared__ __align__(16) short KsD[2][64 * 256];       // 2 x 32 KB  K rows
  __shared__ __align__(16) short VtD[2][2 * 256 * 32];   // 2 x 32 KB  V^T halves

  const int i0 = blockIdx.x;
  const int x8 = i0 & 7;            // XCD id (heuristic: round-robin dispatch)
  const int s  = i0 >> 3;           // 0..31
  const int b  = x8 + 8 * (s & 7);  // batches = x8 (mod 8) cluster on XCD x8
  const int t  = s >> 3;            // 0..3 -> q-tile pair (t, 7-t)

  const int tid  = threadIdx.x;
  const int w    = tid >> 6;        // 0..7
  const int lane = tid & 63;
  const int quad = lane >> 4;
  const int r    = lane & 15;

  const int h0len = 2 * (t + 1);    // ascending tiles for qt=t

  // ---- state for current q-tile
  int qt   = t;
  int n0   = qt * 128 + w * 16;
  int qrow = n0 + r;
  short8 qf[8];
  {
    const short* qp = xk + (size_t)(b * 1024 + qrow) * 256;
#pragma unroll
    for (int ks = 0; ks < 8; ++ks)
      qf[ks] = *(const short8*)(qp + (((ks * 4 + quad) ^ (qrow & 31)) << 3));
  }
  f32x4 Oa[16];
#pragma unroll
  for (int ct = 0; ct < 16; ++ct) Oa[ct] = (f32x4){0.f, 0.f, 0.f, 0.f};
  float m = NEGF, l = 0.f;

  // prefetch tile 0 into buf 0 (64-key tile: 32 KB K + 32 KB V, linear DMA)
  {
    const short* gk = xk + (size_t)(b * 1024) * 256;
    const short* gv = xv + (size_t)(b * 32) * 8192;
#pragma unroll
    for (int u = 0; u < 4; ++u) {
      int seg = w * 4 + u;          // 0..31, 1 KB each
      async16(gk + seg * 512 + lane * 8, &KsD[0][seg * 512]);
      async16(gv + seg * 512 + lane * 8, &VtD[0][seg * 512]);
    }
  }
  __syncthreads();

  for (int idx = 0; idx < 18; ++idx) {
    const int ibuf = idx & 1;
    if (idx < 17) {   // async prefetch tile(idx+1) into other buffer
      const int nt2 = (idx + 1 < h0len) ? (idx + 1) : (17 - (idx + 1));
      const short* gk = xk + (size_t)(b * 1024 + nt2 * 64) * 256;
      const short* gv = xv + (size_t)(b * 32 + nt2 * 2) * 8192;
#pragma unroll
      for (int u = 0; u < 4; ++u) {
        int seg = w * 4 + u;
        async16(gk + seg * 512 + lane * 8, &KsD[1 - ibuf][seg * 512]);
        async16(gv + seg * 512 + lane * 8, &VtD[1 - ibuf][seg * 512]);
      }
    }

    const int kt  = (idx < h0len) ? idx : (17 - idx);
    const int ktb = kt * 64;
    if (ktb <= n0 + 15) {   // wave-uniform causal tile skip
      // ---- scores S^T = K·Q^T  (64 keys = 4 m-tiles)
      float sc[16];
#pragma unroll
      for (int mt = 0; mt < 4; ++mt) {
        f32x4 acc = (f32x4){0.f, 0.f, 0.f, 0.f};
        const int row = mt * 16 + r;
#pragma unroll
        for (int ks = 0; ks < 8; ++ks) {
          short8 af = *(short8*)&KsD[ibuf][row * 256 + (((ks * 4 + quad) ^ (row & 31)) << 3)];
          acc = __builtin_amdgcn_mfma_f32_16x16x32_bf16(af, qf[ks], acc, 0, 0, 0);
        }
        const int j0 = ktb + mt * 16 + quad * 4;
        float4 sA = *(const float4*)(sb + (size_t)b * 1024 + j0);     // s0,b0,s1,b1
        float4 sB = *(const float4*)(sb + (size_t)b * 1024 + j0 + 2); // s2,b2,s3,b3
        sc[mt * 4 + 0] = acc[0] * sA.x + sA.y;
        sc[mt * 4 + 1] = acc[1] * sA.z + sA.w;
        sc[mt * 4 + 2] = acc[2] * sB.x + sB.y;
        sc[mt * 4 + 3] = acc[3] * sB.z + sB.w;
      }
      if (ktb + 63 > n0) {   // diagonal tiles: elementwise causal mask
#pragma unroll
        for (int k2 = 0; k2 < 16; ++k2) {
          int j = ktb + (k2 >> 2) * 16 + quad * 4 + (k2 & 3);
          if (j > qrow) sc[k2] = NEGF;
        }
      }

      // ---- online softmax (stats per q at lane&15, replicated via xor16/32)
      float mx = sc[0];
#pragma unroll
      for (int k2 = 1; k2 < 16; ++k2) mx = fmaxf(mx, sc[k2]);
      mx = fmaxf(mx, __shfl_xor(mx, 16, 64));
      mx = fmaxf(mx, __shfl_xor(mx, 32, 64));
      float mnew  = fmaxf(m, mx);
      float alpha = __expf(m - mnew);   // NEGF-NEGF=0 -> 1; NEGF-real -> 0
      float p[16], ps = 0.f;
#pragma unroll
      for (int k2 = 0; k2 < 16; ++k2) { p[k2] = __expf(sc[k2] - mnew); ps += p[k2]; }
      ps += __shfl_xor(ps, 16, 64);
      ps += __shfl_xor(ps, 32, 64);
      l = l * alpha + ps;
      m = mnew;

      if (__ballot(alpha < 1.0f)) {   // skip rescale when no max update anywhere
        float ar[4];
#pragma unroll
        for (int reg = 0; reg < 4; ++reg) ar[reg] = __shfl(alpha, quad * 4 + reg, 64);
#pragma unroll
        for (int ct = 0; ct < 16; ++ct) {
          Oa[ct][0] *= ar[0]; Oa[ct][1] *= ar[1];
          Oa[ct][2] *= ar[2]; Oa[ct][3] *= ar[3];
        }
      }

      // ---- P (C-layout) -> two PV A-frags via 8 shuffles each
      S8 pf[2];
#pragma unroll
      for (int hh = 0; hh < 2; ++hh) {
        unsigned q0 = pk2(p[hh * 8 + 0], p[hh * 8 + 1]);
        unsigned q1 = pk2(p[hh * 8 + 2], p[hh * 8 + 3]);
        unsigned q2 = pk2(p[hh * 8 + 4], p[hh * 8 + 5]);
        unsigned q3 = pk2(p[hh * 8 + 6], p[hh * 8 + 7]);
        int s0l = ((quad & 1) << 5) + r, s1l = s0l + 16;
        unsigned u0 = __shfl((int)q0, s0l, 64), u1 = __shfl((int)q1, s0l, 64);
        unsigned u2 = __shfl((int)q2, s0l, 64), u3 = __shfl((int)q3, s0l, 64);
        unsigned v0 = __shfl((int)q0, s1l, 64), v1 = __shfl((int)q1, s1l, 64);
        unsigned v2 = __shfl((int)q2, s1l, 64), v3 = __shfl((int)q3, s1l, 64);
        bool hi = quad >= 2;
        pf[hh].w[0] = hi ? u2 : u0; pf[hh].w[1] = hi ? u3 : u1;
        pf[hh].w[2] = hi ? v2 : v0; pf[hh].w[3] = hi ? v3 : v1;
      }

      // ---- PV: O[q][c] += P[q][j] V[j][c]  (two 32-key halves)
#pragma unroll
      for (int ct = 0; ct < 16; ++ct) {
        int c = ct * 16 + r;
        int cs_off = c * 32 + (((quad ^ ((c >> 1) & 3)) & 3) << 3);
        short8 b0 = *(short8*)&VtD[ibuf][cs_off];
        short8 b1 = *(short8*)&VtD[ibuf][8192 + cs_off];
        Oa[ct] = __builtin_amdgcn_mfma_f32_16x16x32_bf16(pf[0].v, b0, Oa[ct], 0, 0, 0);
        Oa[ct] = __builtin_amdgcn_mfma_f32_16x16x32_bf16(pf[1].v, b1, Oa[ct], 0, 0, 0);
      }
    }

    // ---- boundary: finalize qt=t, reset state for qt=7-t (no LDS touched)
    if (idx == h0len - 1) {
      finalize_tile(Oa, m, l, b, quad, r, colsum, gamma, beta, accum);
      qt = 7 - t;
      n0 = qt * 128 + w * 16;
      qrow = n0 + r;
      const short* qp = xk + (size_t)(b * 1024 + qrow) * 256;
#pragma unroll
      for (int ks = 0; ks < 8; ++ks)
        qf[ks] = *(const short8*)(qp + (((ks * 4 + quad) ^ (qrow & 31)) << 3));
#pragma unroll
      for (int ct = 0; ct < 16; ++ct) Oa[ct] = (f32x4){0.f, 0.f, 0.f, 0.f};
      m = NEGF; l = 0.f;
    }

    __syncthreads();   // drains prefetched tile(idx+1) (issued a full tile ago)
  } // idx

  // ---- finalize second q-tile (qt = 7-t)
  finalize_tile(Oa, m, l, b, quad, r, colsum, gamma, beta, accum);
}

// ---------------- launch ----------------

extern "C" void kernel_launch(void* const* d_in, const int* in_sizes, int n_in,
                              void* d_out, int out_size, void* d_ws, size_t ws_size,
                              hipStream_t stream) {
  const float* x     = (const float*)d_in[0];
  const void*  km    = d_in[1];
  const float* gamma = (const float*)d_in[2];
  const float* beta  = (const float*)d_in[3];
  float* out = (float*)d_out;

  // ws layout
  const size_t off_sb = 131200;                       // float2[B*T] = 512 KB
  const size_t off_xk = 655616;                       // 32 MB bf16 K-image
  const size_t off_xv = off_xk + 33554432;            // 32 MB bf16 V^T-image

  float*  accum  = (float*)d_ws;
  float*  colsum = (float*)((char*)d_ws + 65536);
  int*    flag   = (int*)((char*)d_ws + 131072);
  float2* sb     = (float2*)((char*)d_ws + off_sb);
  short*  xk     = (short*)((char*)d_ws + off_xk);
  short*  xv     = (short*)((char*)d_ws + off_xv);

  hipMemsetAsync(d_ws, 0, 131136, stream);   // accum + colsum + flag
  detect_kernel<<<64, 256, 0, stream>>>((const unsigned int*)km, flag);
  convert_kv<<<B_ * 32, 256, 0, stream>>>(x, (const unsigned int*)km, flag,
                                          xk, xv, colsum, sb);
  flash5<<<256, 512, 0, stream>>>(xk, xv, sb, gamma, beta, colsum, accum);
  finalize_kernel<<<B_ * C_ / 256, 256, 0, stream>>>(accum, out);
}